// Round 9
// baseline (81.970 us; speedup 1.0000x reference)
//
#include <hip/hip_runtime.h>
#include <stdint.h>

#define IMG_H 512
#define IMG_W 512
#define NB 16
#define NC 8
#define HW (IMG_H * IMG_W)

#define TILE 64
#define HALO 15
#define CROWS 94                      // dilation rows (rel -15..78)
#define TROWS 96                      // target patch rows (rel -16..79)
#define TCOLS 96                      // target patch cols (rel -16..79)
#define TSTRIDE 100                   // LDS row stride bytes (25 words, odd)
#define NTASK (CROWS * 3)             // 282 (row,word) tasks
#define NBLK (NB * 64)                // 1024 blocks (16 img x 8x8 tiles)

typedef float f4 __attribute__((ext_vector_type(4)));

// Consume one loaded plane (quad-group G, class C) into online-softmax state.
// G and C are compile-time constants after full unroll -> static indexing.
#define CONSUME(G, C, V)  do {                                                \
    uint32_t tw_ = (G) == 0 ? tw0 : (G) == 1 ? tw1 : (G) == 2 ? tw2 : tw3;    \
    _Pragma("unroll")                                                         \
    for (int j = 0; j < 4; j++) {                                             \
        float v_ = (V)[j];                                                    \
        if ((C) == 0) {                                                       \
            m_[G][j] = v_; s_[G][j] = 1.0f; lt_[G][j] = v_;                   \
        } else {                                                              \
            float mn_ = fmaxf(m_[G][j], v_);                                  \
            s_[G][j] = s_[G][j] * __expf(m_[G][j] - mn_) + __expf(v_ - mn_);  \
            m_[G][j] = mn_;                                                   \
            int tc_ = (int)((tw_ >> (8 * j)) & 0xFFu);                        \
            lt_[G][j] = (tc_ == (C)) ? v_ : lt_[G][j];                        \
        }                                                                     \
    }                                                                         \
} while (0)

// ---------------------------------------------------------------------------
// FULLY FUSED: boundary + distance transform + weighted CE, one 64x64 tile
// per block (1024 blocks, 256 threads), with the logits stream INTERLEAVED
// into the dilation loop so memory stays busy during the barrier epoch:
//   P0: clamp-load 96x96 target patch -> LDS (exact: clamp==compare-to-self)
//   P1: boundary bit-words (word-parallel XOR trick), level-0 in cur[0]
//   P2 x15 (unrolled): issue 2 plane-loads -> one dilation step
//       (double-buffered cur, ONE barrier/iter) -> new bits accumulate into
//       4 dist BIT-PLANES in registers (no per-bit ffs/byte stores)
//       -> fold loaded planes into online-softmax (m,s,lt) registers
//   P3: publish bit-planes to LDS, decode per-pixel dist, weight, reduce.
// ---------------------------------------------------------------------------
__global__ __launch_bounds__(256) void distce_kernel(const float* __restrict__ in,
                                                     const int* __restrict__ tgt,
                                                     float* __restrict__ partials) {
    __shared__ uint8_t  tg[TROWS][TSTRIDE];     // 9600 B
    __shared__ uint32_t cur[2][CROWS][5];       // 3760 B, stride 5 (odd)
    __shared__ uint32_t dplanes[TILE][3][4];    // 3072 B
    int b   = blockIdx.x >> 6;
    int tid = blockIdx.x & 63;
    int ty = tid >> 3, tx = tid & 7;
    int ry = ty * TILE, rx = tx * TILE;
    int t = threadIdx.x;
    const int* tgtb = tgt + (size_t)b * HW;

    // ---- P0: clamp-load 96x96 target patch ----
    #pragma unroll
    for (int k = 0; k < 36; k++) {
        int tau = t + 256 * k;
        int r = tau / TCOLS, c = tau % TCOLS;
        int gy = min(max(ry - 16 + r, 0), IMG_H - 1);
        int gx = min(max(rx - 16 + c, 0), IMG_W - 1);
        tg[r][c] = (uint8_t)tgtb[gy * IMG_W + gx];
    }
    __syncthreads();

    // ---- P1: boundary words (level 0). word w bit i <-> rel col 32w+i-16 ----
    auto bword = [&](int r, int w) -> uint32_t {
        int rr = r + 1;
        int gy = ry - 15 + r;
        uint32_t word = 0u;
        if (gy >= 0 && gy < IMG_H) {
            uint32_t Wc[10], Wa[10], Wb[10];
            const uint32_t* pc = (const uint32_t*)&tg[rr][0];
            const uint32_t* pa = (const uint32_t*)&tg[rr - 1][0];
            const uint32_t* pb = (const uint32_t*)&tg[rr + 1][0];
            #pragma unroll
            for (int k = 0; k < 10; k++) {
                int idx = 8 * w - 1 + k;
                idx = min(max(idx, 0), 23);
                Wc[k] = pc[idx]; Wa[k] = pa[idx]; Wb[k] = pb[idx];
            }
            #pragma unroll
            for (int i = 0; i < 8; i++) {
                uint32_t T = Wc[i + 1];
                uint32_t L = (Wc[i + 1] << 8) | (Wc[i] >> 24);
                uint32_t R = (Wc[i + 1] >> 8) | (Wc[i + 2] << 24);
                uint32_t a = (T ^ L) | (T ^ R);
                uint32_t C2 = Wa[i + 1];
                uint32_t L2 = (Wa[i + 1] << 8) | (Wa[i] >> 24);
                uint32_t R2 = (Wa[i + 1] >> 8) | (Wa[i + 2] << 24);
                a |= (T ^ C2) | (T ^ L2) | (T ^ R2);
                uint32_t C3 = Wb[i + 1];
                uint32_t L3 = (Wb[i + 1] << 8) | (Wb[i] >> 24);
                uint32_t R3 = (Wb[i + 1] >> 8) | (Wb[i + 2] << 24);
                a |= (T ^ C3) | (T ^ L3) | (T ^ R3);
                uint32_t t1  = (a & 0x7F7F7F7Fu) + 0x7F7F7F7Fu;
                uint32_t nzb = ((t1 | a) & 0x80808080u) >> 7;
                word |= (((nzb * 0x01020408u) >> 24) & 0xFu) << (4 * i);
            }
            if (tx == 0 && w == 0) word &= 0xFFFF0000u;   // gx<0
            if (tx == 7 && w == 2) word &= 0x0000FFFFu;   // gx>=512
        }
        return word;
    };
    int r0 = t / 3, w0 = t % 3;
    uint32_t o0 = bword(r0, w0);
    cur[0][r0][w0] = o0;
    bool has1 = (t + 256) < NTASK;
    int r1 = (t + 256) / 3, w1 = (t + 256) % 3;
    if (has1) cur[0][r1][w1] = bword(r1, w1);
    uint32_t lm0 = (w0 == 0) ? 0xFFFF0000u : (w0 == 1) ? 0xFFFFFFFFu : 0x0000FFFFu;

    // ---- CE prologue: classes stream as 8px/thread x 4 quad-groups ----
    const float* inb = in + (size_t)b * NC * HW;
    int prow = t >> 4, pquad = t & 15;
    const float* pbase = inb + (size_t)(ry + prow) * IMG_W + rx + pquad * 4;
    uint32_t tw0 = ((const uint32_t*)&tg[16 + prow][0])[4 + pquad];
    uint32_t tw1 = ((const uint32_t*)&tg[32 + prow][0])[4 + pquad];
    uint32_t tw2 = ((const uint32_t*)&tg[48 + prow][0])[4 + pquad];
    uint32_t tw3 = ((const uint32_t*)&tg[64 + prow][0])[4 + pquad];
    float m_[4][4], s_[4][4], lt_[4][4];
    {   // k=0 (g0,c0), k=1 (g1,c0)
        f4 v0 = *(const f4*)(pbase);
        f4 v1 = *(const f4*)(pbase + 16 * IMG_W);
        CONSUME(0, 0, v0);
        CONSUME(1, 0, v1);
    }
    __syncthreads();   // cur[0] ready

    // ---- P2: 15 dilations, 1 barrier each, stream interleaved ----
    uint32_t db0 = 0u, db1 = 0u, db2 = 0u, db3 = 0u;
    #pragma unroll
    for (int it = 1; it <= 15; ++it) {
        const int k0 = 2 * it, k1 = 2 * it + 1;
        const int c0 = k0 >> 2, g0 = k0 & 3;
        const int c1 = k1 >> 2, g1 = k1 & 3;
        f4 vX = *(const f4*)(pbase + (size_t)c0 * HW + g0 * 16 * IMG_W);
        f4 vY = *(const f4*)(pbase + (size_t)c1 * HW + g1 * 16 * IMG_W);

        const int pr = (it + 1) & 1, pw = it & 1;
        uint32_t n0 = 0u;
        #pragma unroll
        for (int dr = -1; dr <= 1; dr++) {
            int rr = r0 + dr;
            if ((unsigned)rr >= (unsigned)CROWS) continue;
            uint32_t vv = cur[pr][rr][w0];
            uint32_t lf = (w0 > 0) ? cur[pr][rr][w0 - 1] : 0u;
            uint32_t rg = (w0 < 2) ? cur[pr][rr][w0 + 1] : 0u;
            n0 |= vv | (vv << 1) | (vv >> 1) | (lf >> 31) | (rg << 31);
        }
        cur[pw][r0][w0] = n0;
        uint32_t nb = (n0 & ~o0) & lm0;
        o0 = n0;
        if (it & 1) db0 |= nb;
        if (it & 2) db1 |= nb;
        if (it & 4) db2 |= nb;
        if (it & 8) db3 |= nb;
        if (has1) {
            uint32_t n1 = 0u;
            #pragma unroll
            for (int dr = -1; dr <= 1; dr++) {
                int rr = r1 + dr;
                if ((unsigned)rr >= (unsigned)CROWS) continue;
                uint32_t vv = cur[pr][rr][w1];
                uint32_t lf = (w1 > 0) ? cur[pr][rr][w1 - 1] : 0u;
                uint32_t rg = (w1 < 2) ? cur[pr][rr][w1 + 1] : 0u;
                n1 |= vv | (vv << 1) | (vv >> 1) | (lf >> 31) | (rg << 31);
            }
            cur[pw][r1][w1] = n1;
        }
        if (g0 == 0) CONSUME(0, c0, vX); else if (g0 == 2) CONSUME(2, c0, vX);
        if (g1 == 1) CONSUME(1, c1, vY); else if (g1 == 3) CONSUME(3, c1, vY);
        __syncthreads();
    }

    // ---- P3: publish bit-planes, decode dist, weight, reduce ----
    int lrow = r0 - HALO;
    if ((unsigned)lrow < (unsigned)TILE) {
        dplanes[lrow][w0][0] = db0;
        dplanes[lrow][w0][1] = db1;
        dplanes[lrow][w0][2] = db2;
        dplanes[lrow][w0][3] = db3;
    }
    __syncthreads();

    float partial = 0.0f;
    int bitbase = 4 * pquad + 16;
    int wsel = bitbase >> 5, sh = bitbase & 31;
    #pragma unroll
    for (int g = 0; g < 4; g++) {
        int row = prow + 16 * g;
        uint4 pl = *(const uint4*)&dplanes[row][wsel][0];
        #pragma unroll
        for (int j = 0; j < 4; j++) {
            int d = ((pl.x >> (sh + j)) & 1) | (((pl.y >> (sh + j)) & 1) << 1)
                  | (((pl.z >> (sh + j)) & 1) << 2) | (((pl.w >> (sh + j)) & 1) << 3);
            float ce = m_[g][j] + __logf(s_[g][j]) - lt_[g][j];
            partial += __expf((float)d * -0.2f) * ce;
        }
    }
    #pragma unroll
    for (int off = 32; off > 0; off >>= 1) partial += __shfl_down(partial, off);
    __shared__ float wsums[4];
    int lane = t & 63;
    int wid = t >> 6;
    if (lane == 0) wsums[wid] = partial;
    __syncthreads();
    if (t == 0)
        partials[blockIdx.x] = wsums[0] + wsums[1] + wsums[2] + wsums[3];
}

// ---------------------------------------------------------------------------
// Deterministic tree-reduce of 1024 partials -> mean. One block.
// ---------------------------------------------------------------------------
__global__ __launch_bounds__(256) void reduce_kernel(const float* __restrict__ partials,
                                                     float* __restrict__ out) {
    double s = 0.0;
    #pragma unroll
    for (int i = 0; i < NBLK / 256; i++)
        s += (double)partials[threadIdx.x + 256 * i];
    #pragma unroll
    for (int off = 32; off > 0; off >>= 1) s += __shfl_down(s, off);
    __shared__ double wsums[4];
    int lane = threadIdx.x & 63;
    int wid = threadIdx.x >> 6;
    if (lane == 0) wsums[wid] = s;
    __syncthreads();
    if (threadIdx.x == 0) {
        double tot = wsums[0] + wsums[1] + wsums[2] + wsums[3];
        out[0] = (float)(tot * (1.0 / (double)((size_t)NB * HW)));
    }
}

extern "C" void kernel_launch(void* const* d_in, const int* in_sizes, int n_in,
                              void* d_out, int out_size, void* d_ws, size_t ws_size,
                              hipStream_t stream) {
    const float* in  = (const float*)d_in[0];
    const int*   tgt = (const int*)d_in[1];
    float* out = (float*)d_out;

    float* partials = (float*)((char*)d_ws + 256);   // 4 KB

    distce_kernel<<<NBLK, 256, 0, stream>>>(in, tgt, partials);
    reduce_kernel<<<1, 256, 0, stream>>>(partials, out);
}

// Round 10
// 32.066 us; speedup vs baseline: 2.5563x; 2.5563x over previous
//
#include <hip/hip_runtime.h>
#include <stdint.h>

#define IMG_H 512
#define IMG_W 512
#define NB 16
#define NC 8
#define HW (IMG_H * IMG_W)

#define TILE 64
#define HALO 15
#define CROWS 94                      // dilation rows (rel -15..78)
#define TROWS 96                      // target patch rows (rel -16..79)
#define TCOLS 96                      // target patch cols (rel -16..79)
#define TSTRIDE 100                   // LDS row stride bytes (25 words, odd)
#define NTASK (CROWS * 3)             // 282 (row,word) tasks
#define NBLK (NB * 64)                // 1024 blocks (16 img x 8x8 tiles)

typedef float f4 __attribute__((ext_vector_type(4)));

// ---------------------------------------------------------------------------
// FULLY FUSED: boundary + distance transform + weighted CE per 64x64 tile
// (R7 structure, 36 VGPR, restored after R9's 200-VGPR interleave regression).
// NEW: fixed-point early exit. dtile writes are monotone: once every inner
// bit of cur is 1, no further dtile update can occur, so the remaining
// iterations are skipped (block-uniform via __syncthreads_count). For random
// 8-class targets P(non-boundary px) ~ 6e-8 -> level 0 is already saturated
// and the whole 30-barrier dilation epoch collapses to one check. Exact for
// all inputs (saturation is a fixed point of dilation).
// ---------------------------------------------------------------------------
__global__ __launch_bounds__(256) void distce_kernel(const float* __restrict__ in,
                                                     const int* __restrict__ tgt,
                                                     float* __restrict__ partials) {
    __shared__ uint8_t  tg[TROWS][TSTRIDE];   // 9600 B
    __shared__ uint32_t cur[2][CROWS][5];     // 3760 B (double buffer, stride 5)
    __shared__ uint8_t  dtile[TILE][TILE];    // 4096 B
    int b   = blockIdx.x >> 6;
    int tid = blockIdx.x & 63;
    int ty = tid >> 3, tx = tid & 7;
    int ry = ty * TILE, rx = tx * TILE;
    int t = threadIdx.x;
    const int* tgtb = tgt + (size_t)b * HW;

    ((uint4*)dtile)[t] = make_uint4(0u, 0u, 0u, 0u);

    // ---- P0: load 96x96 target patch -> LDS bytes ----
    // x-interior tiles (tx 1..6): int4 rows (aligned: rx-16 multiple of 16).
    // x-edge tiles: scalar clamped path. Row clamp is free in both.
    if (tx >= 1 && tx <= 6) {
        #pragma unroll
        for (int k = 0; k < 9; k++) {
            int tau = t + 256 * k;            // 2304 = 96 rows x 24 int4
            int r = tau / 24, c4 = tau % 24;
            int gy = min(max(ry - 16 + r, 0), IMG_H - 1);
            const int4* rowp = (const int4*)(tgtb + (size_t)gy * IMG_W + rx - 16);
            int4 v = rowp[c4];
            ((uint32_t*)&tg[r][0])[c4] =
                (uint32_t)(v.x & 255) | ((uint32_t)(v.y & 255) << 8) |
                ((uint32_t)(v.z & 255) << 16) | ((uint32_t)(v.w & 255) << 24);
        }
    } else {
        #pragma unroll
        for (int k = 0; k < 36; k++) {
            int tau = t + 256 * k;
            int r = tau / TCOLS, c = tau % TCOLS;
            int gy = min(max(ry - 16 + r, 0), IMG_H - 1);
            int gx = min(max(rx - 16 + c, 0), IMG_W - 1);
            tg[r][c] = (uint8_t)tgtb[gy * IMG_W + gx];
        }
    }
    __syncthreads();

    // ---- P1: boundary bit-words (word-parallel XOR trick, verified R6-R8) ----
    auto bword = [&](int r, int w) -> uint32_t {
        int rr = r + 1;
        int gy = ry - 15 + r;
        uint32_t word = 0u;
        if (gy >= 0 && gy < IMG_H) {
            uint32_t Wc[10], Wa[10], Wb[10];
            const uint32_t* pc = (const uint32_t*)&tg[rr][0];
            const uint32_t* pa = (const uint32_t*)&tg[rr - 1][0];
            const uint32_t* pb = (const uint32_t*)&tg[rr + 1][0];
            #pragma unroll
            for (int k = 0; k < 10; k++) {
                int idx = 8 * w - 1 + k;
                idx = min(max(idx, 0), 23);
                Wc[k] = pc[idx]; Wa[k] = pa[idx]; Wb[k] = pb[idx];
            }
            #pragma unroll
            for (int i = 0; i < 8; i++) {
                uint32_t T = Wc[i + 1];
                uint32_t L = (Wc[i + 1] << 8) | (Wc[i] >> 24);
                uint32_t R = (Wc[i + 1] >> 8) | (Wc[i + 2] << 24);
                uint32_t a = (T ^ L) | (T ^ R);
                uint32_t C2 = Wa[i + 1];
                uint32_t L2 = (Wa[i + 1] << 8) | (Wa[i] >> 24);
                uint32_t R2 = (Wa[i + 1] >> 8) | (Wa[i + 2] << 24);
                a |= (T ^ C2) | (T ^ L2) | (T ^ R2);
                uint32_t C3 = Wb[i + 1];
                uint32_t L3 = (Wb[i + 1] << 8) | (Wb[i] >> 24);
                uint32_t R3 = (Wb[i + 1] >> 8) | (Wb[i + 2] << 24);
                a |= (T ^ C3) | (T ^ L3) | (T ^ R3);
                uint32_t t1  = (a & 0x7F7F7F7Fu) + 0x7F7F7F7Fu;
                uint32_t nzb = ((t1 | a) & 0x80808080u) >> 7;
                word |= (((nzb * 0x01020408u) >> 24) & 0xFu) << (4 * i);
            }
            if (tx == 0 && w == 0) word &= 0xFFFF0000u;   // gx<0 not in image
            if (tx == 7 && w == 2) word &= 0x0000FFFFu;   // gx>=512 not in image
        }
        return word;
    };
    int r0 = t / 3, w0 = t % 3;
    uint32_t o0 = bword(r0, w0);
    cur[0][r0][w0] = o0;
    bool has1 = (t + 256) < NTASK;
    int r1 = (t + 256) / 3, w1 = (t + 256) % 3;
    if (has1) cur[0][r1][w1] = bword(r1, w1);   // rows 85..93: never inner
    uint32_t lm0 = (w0 == 0) ? 0xFFFF0000u : (w0 == 1) ? 0xFFFFFFFFu : 0x0000FFFFu;
    bool inner0 = (r0 >= HALO && r0 < HALO + TILE);

    // ---- P2: dilations with fixed-point early exit ----
    // (also the barrier publishing cur[0] / dtile zero-init)
    int cnt = __syncthreads_count(inner0 && ((o0 | ~lm0) != 0xFFFFFFFFu));
    if (cnt != 0) {
        for (int it = 1; it <= 15; ++it) {
            int pr = (it + 1) & 1, pw = it & 1;
            uint32_t n0 = 0u;
            #pragma unroll
            for (int dr = -1; dr <= 1; dr++) {
                int rr = r0 + dr;
                if ((unsigned)rr >= (unsigned)CROWS) continue;
                uint32_t vv = cur[pr][rr][w0];
                uint32_t lf = (w0 > 0) ? cur[pr][rr][w0 - 1] : 0u;
                uint32_t rg = (w0 < 2) ? cur[pr][rr][w0 + 1] : 0u;
                n0 |= vv | (vv << 1) | (vv >> 1) | (lf >> 31) | (rg << 31);
            }
            cur[pw][r0][w0] = n0;
            uint32_t nb = (n0 & ~o0) & lm0;
            o0 = n0;
            if (inner0) {
                uint32_t x = nb;
                while (x) { int bit = __ffs(x) - 1; x &= x - 1;
                            dtile[r0 - HALO][w0 * 32 + bit - 16] = (uint8_t)it; }
            }
            if (has1) {
                uint32_t n1 = 0u;
                #pragma unroll
                for (int dr = -1; dr <= 1; dr++) {
                    int rr = r1 + dr;
                    if ((unsigned)rr >= (unsigned)CROWS) continue;
                    uint32_t vv = cur[pr][rr][w1];
                    uint32_t lf = (w1 > 0) ? cur[pr][rr][w1 - 1] : 0u;
                    uint32_t rg = (w1 < 2) ? cur[pr][rr][w1 + 1] : 0u;
                    n1 |= vv | (vv << 1) | (vv >> 1) | (lf >> 31) | (rg << 31);
                }
                cur[pw][r1][w1] = n1;
            }
            // barrier + saturation vote (dtile stores above are covered)
            cnt = __syncthreads_count(inner0 && ((n0 | ~lm0) != 0xFFFFFFFFu));
            if (cnt == 0) break;
        }
    }

    // ---- P3: CE over the tile (16 px/thread), dist from LDS, reduce ----
    float partial = 0.0f;
    const float* inb = in + (size_t)b * NC * HW;
    #pragma unroll
    for (int g = 0; g < 4; g++) {
        int q = t + 256 * g;
        int row = q >> 4, quad = q & 15;
        const float* base = inb + (size_t)(ry + row) * IMG_W + rx + quad * 4;
        float v[NC][4];
        #pragma unroll
        for (int c = 0; c < NC; c++) {
            f4 f = *(const f4*)(base + (size_t)c * HW);
            v[c][0] = f.x; v[c][1] = f.y; v[c][2] = f.z; v[c][3] = f.w;
        }
        uint32_t tw = ((const uint32_t*)&tg[16 + row][0])[4 + quad];
        uint32_t d4 = *(const uint32_t*)&dtile[row][quad * 4];
        #pragma unroll
        for (int j = 0; j < 4; j++) {
            float mx = v[0][j];
            #pragma unroll
            for (int c = 1; c < NC; c++) mx = fmaxf(mx, v[c][j]);
            float s = 0.0f;
            #pragma unroll
            for (int c = 0; c < NC; c++) s += __expf(v[c][j] - mx);
            float lse = mx + __logf(s);
            int tc = (int)((tw >> (8 * j)) & 0xFFu);
            float lt = v[0][j];
            #pragma unroll
            for (int c = 1; c < NC; c++) lt = (tc == c) ? v[c][j] : lt;
            float ce = lse - lt;
            float d = (float)((d4 >> (8 * j)) & 0xFFu);
            partial += __expf(d * -0.2f) * ce;
        }
    }
    #pragma unroll
    for (int off = 32; off > 0; off >>= 1) partial += __shfl_down(partial, off);
    __shared__ float wsums[4];
    int lane = t & 63;
    int wid = t >> 6;
    if (lane == 0) wsums[wid] = partial;
    __syncthreads();
    if (t == 0)
        partials[blockIdx.x] = wsums[0] + wsums[1] + wsums[2] + wsums[3];
}

// ---------------------------------------------------------------------------
// Deterministic tree-reduce of 1024 partials -> mean. One block.
// ---------------------------------------------------------------------------
__global__ __launch_bounds__(256) void reduce_kernel(const float* __restrict__ partials,
                                                     float* __restrict__ out) {
    double s = 0.0;
    #pragma unroll
    for (int i = 0; i < NBLK / 256; i++)
        s += (double)partials[threadIdx.x + 256 * i];
    #pragma unroll
    for (int off = 32; off > 0; off >>= 1) s += __shfl_down(s, off);
    __shared__ double wsums[4];
    int lane = threadIdx.x & 63;
    int wid = threadIdx.x >> 6;
    if (lane == 0) wsums[wid] = s;
    __syncthreads();
    if (threadIdx.x == 0) {
        double tot = wsums[0] + wsums[1] + wsums[2] + wsums[3];
        out[0] = (float)(tot * (1.0 / (double)((size_t)NB * HW)));
    }
}

extern "C" void kernel_launch(void* const* d_in, const int* in_sizes, int n_in,
                              void* d_out, int out_size, void* d_ws, size_t ws_size,
                              hipStream_t stream) {
    const float* in  = (const float*)d_in[0];
    const int*   tgt = (const int*)d_in[1];
    float* out = (float*)d_out;

    float* partials = (float*)((char*)d_ws + 256);   // 4 KB

    distce_kernel<<<NBLK, 256, 0, stream>>>(in, tgt, partials);
    reduce_kernel<<<1, 256, 0, stream>>>(partials, out);
}